// Round 8
// baseline (292.119 us; speedup 1.0000x reference)
//
#include <hip/hip_runtime.h>
#include <math.h>

typedef __bf16 bf16_t;
typedef __bf16 bf16x8 __attribute__((ext_vector_type(8)));
typedef float f32x4 __attribute__((ext_vector_type(4)));

#define GLOAD_LDS16(g, l)                                                      \
  __builtin_amdgcn_global_load_lds(                                            \
      (const __attribute__((address_space(1))) void*)(g),                      \
      (__attribute__((address_space(3))) void*)(l), 16, 0, 0)

// ---------------------------------------------------------------------------
// Prep: build bf16 operands.
// ---------------------------------------------------------------------------
__global__ __launch_bounds__(256) void prep_kernel(
    const float* __restrict__ enc, const float* __restrict__ dec,
    const float* __restrict__ ot, const float* __restrict__ W_enc,
    const float* __restrict__ W_ot, const float* __restrict__ W_dec,
    const float* __restrict__ W_out, bf16_t* __restrict__ Acat,
    bf16_t* __restrict__ Dec, bf16_t* __restrict__ WcatT,
    bf16_t* __restrict__ WdecT, bf16_t* __restrict__ WoutT) {
  int idx = blockIdx.x * 256 + threadIdx.x;
  const int N0 = 1600 * 1024, N1 = 400 * 512, N2 = 640 * 1024, N3 = 640 * 512,
            N4 = 1024 * 640;
  if (idx < N0) {
    int r = idx >> 10, c = idx & 1023;
    float v = (c < 512) ? enc[(r << 9) + c] : ot[(r << 9) + (c - 512)];
    Acat[idx] = (bf16_t)v;
    return;
  }
  idx -= N0;
  if (idx < N1) {
    Dec[idx] = (bf16_t)dec[idx];
    return;
  }
  idx -= N1;
  if (idx < N2) {
    int f = idx >> 10, k = idx & 1023;
    float v = (k < 512) ? W_enc[k * 640 + f] : W_ot[(k - 512) * 640 + f];
    WcatT[idx] = (bf16_t)v;
    return;
  }
  idx -= N2;
  if (idx < N3) {
    int f = idx >> 9, k = idx & 511;
    WdecT[idx] = (bf16_t)W_dec[k * 640 + f];
    return;
  }
  idx -= N3;
  if (idx < N4) {
    int v = idx / 640, f = idx - v * 640;
    WoutT[idx] = (bf16_t)W_out[f * 1024 + v];
    return;
  }
}

// ---------------------------------------------------------------------------
// Stage 1: out[M][640] = tanh(A[M][K] @ Bt[640][K]^T + bias1 (+ bias2))
// ---------------------------------------------------------------------------
__global__ __launch_bounds__(256) void gemm_tanh_kernel(
    const bf16_t* __restrict__ A, const bf16_t* __restrict__ Bt,
    const float* __restrict__ bias1, const float* __restrict__ bias2,
    float* __restrict__ out, int M, int K) {
  __shared__ bf16_t As[64 * 32];
  __shared__ bf16_t Bs[64 * 32];
  const int tid = threadIdx.x;
  const int wid = tid >> 6, lane = tid & 63;
  const int wm = wid >> 1, wn = wid & 1;
  const int r0 = blockIdx.y * 64, n0 = blockIdx.x * 64;

  const int ia = wid * 16 + (lane >> 2);
  const int sa = lane & 3;
  int ra = r0 + ia;
  if (ra > M - 1) ra = M - 1;
  const bf16_t* gA = A + (size_t)ra * K + sa * 8;
  const bf16_t* gB = Bt + (size_t)(n0 + ia) * K + sa * 8;
  bf16_t* lA = As + wid * 512;
  bf16_t* lB = Bs + wid * 512;

  f32x4 acc[2][2] = {};
  const int lr = lane & 15, kg = lane >> 4;
  const int steps = K >> 5;
  for (int ks = 0; ks < steps; ++ks) {
    GLOAD_LDS16(gA + ks * 32, lA);
    GLOAD_LDS16(gB + ks * 32, lB);
    __syncthreads();
    bf16x8 af[2], bfr[2];
#pragma unroll
    for (int a = 0; a < 2; ++a)
      af[a] = *(const bf16x8*)(As + (wm * 32 + a * 16 + lr) * 32 + kg * 8);
#pragma unroll
    for (int b = 0; b < 2; ++b)
      bfr[b] = *(const bf16x8*)(Bs + (wn * 32 + b * 16 + lr) * 32 + kg * 8);
#pragma unroll
    for (int a = 0; a < 2; ++a)
#pragma unroll
      for (int b = 0; b < 2; ++b)
        acc[a][b] =
            __builtin_amdgcn_mfma_f32_16x16x32_bf16(af[a], bfr[b], acc[a][b], 0, 0, 0);
    __syncthreads();
  }
#pragma unroll
  for (int a = 0; a < 2; ++a)
#pragma unroll
    for (int b = 0; b < 2; ++b) {
      int col = n0 + wn * 32 + b * 16 + lr;
      float bv = bias1[col] + (bias2 ? bias2[col] : 0.0f);
#pragma unroll
      for (int j = 0; j < 4; ++j) {
        int rg = r0 + wm * 32 + a * 16 + kg * 4 + j;
        if (rg < M) out[(size_t)rg * 640 + col] = tanhf(acc[a][b][j] + bv);
      }
    }
}

// ---------------------------------------------------------------------------
// Materialize joint A: Amat[80128][640] bf16 = tanh(fused+proj_dec) via the
// tanh addition identity. Pad rows zeroed.
// ---------------------------------------------------------------------------
__global__ __launch_bounds__(256) void materialize_joint_kernel(
    const float* __restrict__ ta,   // [1600][640]
    const float* __restrict__ tb,   // [400][640]
    bf16_t* __restrict__ Amat) {    // [80128][640]
  const int idx = blockIdx.x * 256 + threadIdx.x;  // 0 .. 80128*80-1
  const int row = idx / 80;
  const int s = idx - row * 80;
  bf16x8 jv;
  if (row >= 80000) {
#pragma unroll
    for (int e = 0; e < 8; ++e) jv[e] = (bf16_t)0.0f;
    *(bf16x8*)(Amat + (size_t)row * 640 + s * 8) = jv;
    return;
  }
  const int frow = row / 50;          // b*T + t
  const int bidx = row / 10000;       // b
  const int u = row - frow * 50;      // u
  const float* taP = ta + (size_t)frow * 640 + s * 8;
  const float* tbP = tb + (size_t)(bidx * 50 + u) * 640 + s * 8;
#pragma unroll
  for (int h = 0; h < 2; ++h) {
    f32x4 xa = *(const f32x4*)(taP + h * 4);
    f32x4 xb = *(const f32x4*)(tbP + h * 4);
#pragma unroll
    for (int e = 0; e < 4; ++e) {
      float d = fmaxf(1.0f + xa[e] * xb[e], 1e-6f);
      jv[h * 4 + e] = (bf16_t)((xa[e] + xb[e]) * __builtin_amdgcn_rcpf(d));
    }
  }
  *(bf16x8*)(Amat + (size_t)row * 640 + s * 8) = jv;
}

// ---------------------------------------------------------------------------
// Stage 2: m97-geometry joint GEMM (cross-block TLP, m114 mechanism).
//  out[80000][1024] = Amat[80128][640] @ WoutT[1024][640]^T + b_out
//  128x128 tile, 256 thr, 4 waves 2(M)x2(N), wave tile 64x64 of 16x16x32.
//  BK=32 -> 20 K-tiles. Double-buffered 32 KB LDS; plain schedule:
//  issue stage(t+1) -> ds_read+MFMA(t) -> __syncthreads. 3 blocks/CU
//  co-resident overlap each other's drains and epilogue bursts.
//  Swizzle (proven R7, conflicts=0): LDS slot q of row rr holds source
//  col-slot q ^ ((rr>>1)&3); gload source col pre-permuted per-lane by
//  (l&3)^((l>>3)&3); read slot = (l>>4) ^ ((rr>>1)&3).
//  XCD-chunked block remap (5008 = 8 x 626, exact): all 8 N-siblings of
//  an A-panel land on one XCD -> A fetched ~once from HBM.
// ---------------------------------------------------------------------------
__global__ __launch_bounds__(256, 3) void joint_gemm_kernel(
    const bf16_t* __restrict__ Amat,   // [80128][640]
    const bf16_t* __restrict__ WoutT,  // [1024][640]
    const float* __restrict__ b_out,   // [1024]
    float* __restrict__ out) {         // [80000][1024]
  __shared__ __align__(16) unsigned char L[2][16384];  // per buf: A 8K | B 8K
  const int tid = threadIdx.x;
  const int w = tid >> 6, l = tid & 63;
  const int wm = w >> 1, wn = w & 1;

  // XCD-chunked bijective remap: xcd = orig&7 owns 626 consecutive wg.
  const int orig = blockIdx.x;
  const int wg = (orig & 7) * 626 + (orig >> 3);
  const int mb = wg >> 3, nb = wg & 7;
  const int r0 = mb * 128, n0 = nb * 128;

  // ---- staging sources (per-lane, col pre-permuted for swizzle) ----
  const int srow = l >> 2;
  const int perm = ((l & 3) ^ ((l >> 3) & 3)) * 8;  // element offset
  const bf16_t* gA0 = Amat + (size_t)(r0 + w * 16 + srow) * 640 + perm;
  const bf16_t* gA1 = gA0 + (size_t)64 * 640;
  const bf16_t* gB0 = WoutT + (size_t)(n0 + w * 16 + srow) * 640 + perm;
  const bf16_t* gB1 = gB0 + (size_t)64 * 640;
  // wave-uniform LDS dest offsets (HW adds lane*16B): A rows linear rr*64
  const int dA0 = w * 1024, dA1 = dA0 + 4096;
  const int dB0 = 8192 + w * 1024, dB1 = dB0 + 4096;

  // ---- frag read byte offsets (row rr at byte rr*64, swizzled slot) ----
  int aoff[4], boff[4];
#pragma unroll
  for (int f = 0; f < 4; ++f) {
    const int ra = wm * 64 + f * 16 + (l & 15);
    aoff[f] = ra * 64 + (((l >> 4) ^ ((ra >> 1) & 3)) * 16);
    const int rb = wn * 64 + f * 16 + (l & 15);
    boff[f] = 8192 + rb * 64 + (((l >> 4) ^ ((rb >> 1) & 3)) * 16);
  }

  f32x4 acc[4][4] = {};

  // ---- prologue: stage tile 0 into buf 0 ----
  GLOAD_LDS16(gA0, L[0] + dA0);
  GLOAD_LDS16(gA1, L[0] + dA1);
  GLOAD_LDS16(gB0, L[0] + dB0);
  GLOAD_LDS16(gB1, L[0] + dB1);
  __syncthreads();

#pragma unroll 1
  for (int t = 0; t < 20; ++t) {
    const int cur = t & 1, nxt = cur ^ 1;
    // -- issue next-tile stage first (flies during compute) --
    if (t < 19) {
      const size_t ko = (size_t)(t + 1) * 32;
      GLOAD_LDS16(gA0 + ko, L[nxt] + dA0);
      GLOAD_LDS16(gA1 + ko, L[nxt] + dA1);
      GLOAD_LDS16(gB0 + ko, L[nxt] + dB0);
      GLOAD_LDS16(gB1 + ko, L[nxt] + dB1);
    }
    // -- compute current tile --
    bf16x8 af[4], bfr[4];
#pragma unroll
    for (int f = 0; f < 4; ++f) af[f] = *(const bf16x8*)(L[cur] + aoff[f]);
#pragma unroll
    for (int f = 0; f < 4; ++f) bfr[f] = *(const bf16x8*)(L[cur] + boff[f]);
#pragma unroll
    for (int a = 0; a < 4; ++a)
#pragma unroll
      for (int b = 0; b < 4; ++b)
        acc[a][b] = __builtin_amdgcn_mfma_f32_16x16x32_bf16(af[a], bfr[b],
                                                            acc[a][b], 0, 0, 0);
    // -- single drain+barrier per tile; co-resident blocks cover it --
    __syncthreads();
  }

  // ---- epilogue: + b_out, store f32 (16x16 C/D: col=l&15, row=kg*4+j) ----
  const int kg = l >> 4;
#pragma unroll
  for (int b = 0; b < 4; ++b) {
    const int col = n0 + wn * 64 + b * 16 + (l & 15);
    const float bv = b_out[col];
#pragma unroll
    for (int a = 0; a < 4; ++a) {
      const int rg = r0 + wm * 64 + a * 16 + kg * 4;
      float* op = out + (size_t)rg * 1024 + col;
      const f32x4 v = acc[a][b];
#pragma unroll
      for (int j = 0; j < 4; ++j)
        if (rg + j < 80000) op[(size_t)j * 1024] = v[j] + bv;
    }
  }
}

// ---------------------------------------------------------------------------
extern "C" void kernel_launch(void* const* d_in, const int* in_sizes, int n_in,
                              void* d_out, int out_size, void* d_ws,
                              size_t ws_size, hipStream_t stream) {
  const float* enc = (const float*)d_in[0];
  const float* dec = (const float*)d_in[1];
  const float* ot = (const float*)d_in[2];
  const float* W_enc = (const float*)d_in[3];
  const float* b_enc = (const float*)d_in[4];
  const float* W_ot = (const float*)d_in[5];
  const float* b_ot = (const float*)d_in[6];
  const float* W_dec = (const float*)d_in[7];
  const float* b_dec = (const float*)d_in[8];
  const float* W_out = (const float*)d_in[9];
  const float* b_out = (const float*)d_in[10];
  float* out = (float*)d_out;

  char* ws = (char*)d_ws;
  size_t off = 0;
  auto alloc = [&](size_t bytes) {
    void* p = ws + off;
    off += (bytes + 255) & ~(size_t)255;
    return p;
  };
  float* ta = (float*)alloc(1600 * 640 * 4);        // tanh(fused)
  float* tb = (float*)alloc(400 * 640 * 4);         // tanh(proj_dec)
  bf16_t* Acat = (bf16_t*)alloc(1600 * 1024 * 2);
  bf16_t* Dec = (bf16_t*)alloc(400 * 512 * 2);
  bf16_t* WcatT = (bf16_t*)alloc(640 * 1024 * 2);
  bf16_t* WdecT = (bf16_t*)alloc(640 * 512 * 2);
  bf16_t* WoutT = (bf16_t*)alloc(1024 * 640 * 2);
  bf16_t* Amat = (bf16_t*)alloc((size_t)80128 * 640 * 2);  // joint bf16

  prep_kernel<<<13600, 256, 0, stream>>>(enc, dec, ot, W_enc, W_ot, W_dec,
                                         W_out, Acat, Dec, WcatT, WdecT, WoutT);
  gemm_tanh_kernel<<<dim3(10, 25), 256, 0, stream>>>(Acat, WcatT, b_enc, b_ot,
                                                     ta, 1600, 1024);
  gemm_tanh_kernel<<<dim3(10, 7), 256, 0, stream>>>(Dec, WdecT, b_dec, nullptr,
                                                    tb, 400, 512);
  materialize_joint_kernel<<<25040, 256, 0, stream>>>(ta, tb, Amat);
  // joint: 128x128 tiles, 4 waves, dbuf, 3 blocks/CU (m97 geometry)
  joint_gemm_kernel<<<5008, 256, 0, stream>>>(Amat, WoutT, b_out, out);
}